// Round 14
// baseline (93.052 us; speedup 1.0000x reference)
//
#include <hip/hip_runtime.h>

typedef _Float16 h8v __attribute__((ext_vector_type(8)));
typedef _Float16 h4v __attribute__((ext_vector_type(4)));
typedef __fp16 h2v __attribute__((ext_vector_type(2)));   // cvt_pkrtz return type
typedef float f4 __attribute__((ext_vector_type(4)));

constexpr int S = 2048, H = 16, Dd = 64;
constexpr int QB = 256;            // q rows per block (64 per wave)
constexpr int KT = 32, NKT = S / KT;   // 64
constexpr float QSC = 0.18033688011112042f;  // log2(e)/8 folded into Q
constexpr float DIAGL = -150000.0f;          // diag penalty, log2 domain
constexpr size_t KH_ELEMS = (size_t)64 * S * Dd;   // 8M halves = 16 MB
constexpr size_t VG_ELEMS = (size_t)64 * 64 * Dd * 32;  // 16 MB

union H8U { h8v v; h2v h[4]; };

// ---- prepass: K -> f16 row-major; V -> f16 transposed+swizzled tile layout ----
// Vg[bh][kt][d][pos]: pos = chunk*8 + (key&3) + 4*(key>>4), chunk = ((key>>2)&3)^((d>>3)&3)
__global__ __launch_bounds__(256, 2)
void prep(const float* __restrict__ kg, const float* __restrict__ vg,
          _Float16* __restrict__ Kh, _Float16* __restrict__ Vg)
{
  __shared__ float Vs[32][68];
  const int t = threadIdx.x;
  const int bb = (int)blockIdx.x;
  const int bh = bb >> 3, part = bb & 7;
  const int b = bh >> 4, h = bh & 15;
  const int key8 = t >> 3, d8 = (t & 7) * 8;   // load role
  const int vd = t >> 2, vp8 = (t & 3) * 8;    // store role
  const int fdv = (vd >> 3) & 3;

  for (int kt = part * 8; kt < part * 8 + 8; ++kt) {
    const size_t grow = (((size_t)b * S + kt * 32 + key8) * H + h) * Dd + d8;
    // K: straight convert, coalesced
    f4 ka0 = *(const f4*)(kg + grow), ka1 = *(const f4*)(kg + grow + 4);
    H8U uk;
    uk.h[0] = __builtin_amdgcn_cvt_pkrtz(ka0[0], ka0[1]);
    uk.h[1] = __builtin_amdgcn_cvt_pkrtz(ka0[2], ka0[3]);
    uk.h[2] = __builtin_amdgcn_cvt_pkrtz(ka1[0], ka1[1]);
    uk.h[3] = __builtin_amdgcn_cvt_pkrtz(ka1[2], ka1[3]);
    *(h8v*)&Kh[((size_t)bh * S + kt * 32 + key8) * Dd + d8] = uk.v;
    // V: tile to LDS
    f4 va0 = *(const f4*)(vg + grow), va1 = *(const f4*)(vg + grow + 4);
    *(f4*)&Vs[key8][d8] = va0;
    *(f4*)&Vs[key8][d8 + 4] = va1;
    __syncthreads();
    // V^T swizzled: one coalesced 16B write per thread
    float e[8];
    #pragma unroll
    for (int j = 0; j < 8; ++j) {
      const int pos = vp8 + j;
      const int key = ((pos >> 2) & 1) * 16 + (((pos >> 3) ^ fdv) & 3) * 4 + (pos & 3);
      e[j] = Vs[key][vd];
    }
    H8U uv;
    uv.h[0] = __builtin_amdgcn_cvt_pkrtz(e[0], e[1]);
    uv.h[1] = __builtin_amdgcn_cvt_pkrtz(e[2], e[3]);
    uv.h[2] = __builtin_amdgcn_cvt_pkrtz(e[4], e[5]);
    uv.h[3] = __builtin_amdgcn_cvt_pkrtz(e[6], e[7]);
    *(h8v*)&Vg[(((size_t)bh * 64 + kt) * Dd + vd) * 32 + vp8] = uv.v;
    __syncthreads();
  }
}

// ---- main kernel: champion structure, f16 staging (half the stream bytes) ----
__global__ __launch_bounds__(256, 2)
void attn_fwd(const float* __restrict__ qglob, const _Float16* __restrict__ Kh,
              const _Float16* __restrict__ Vg, float* __restrict__ out)
{
  __shared__ _Float16 Kf[2][KT][72];
  __shared__ _Float16 Vt[2][Dd][40];

  const int tid = threadIdx.x;
  const int w = tid >> 6, lane = tid & 63;
  const int g = lane >> 4, c = lane & 15;

  const int vb = ((int)blockIdx.x & 7) * 64 + ((int)blockIdx.x >> 3);  // XCD swizzle
  const int qt = vb & 7, h = (vb >> 3) & 15, b = vb >> 7;
  const int bh = b * 16 + h;
  const int qbase = qt * QB + w * 64;

  // --- Q B-frags; k-slot -> d map: d = g*16 + kk*8 + j ---
  h8v qf[4][2];
  {
    const float* qp = qglob + (((size_t)b * S + qbase + c) * H + h) * Dd + g * 16;
    #pragma unroll
    for (int qg = 0; qg < 4; ++qg) {
      const float* qq = qp + (size_t)qg * 16 * H * Dd;
      #pragma unroll
      for (int kk = 0; kk < 2; ++kk) {
        f4 a  = *(const f4*)(qq + kk * 8);
        f4 bb = *(const f4*)(qq + kk * 8 + 4);
        H8U u;
        u.h[0] = __builtin_amdgcn_cvt_pkrtz(a[0] * QSC, a[1] * QSC);
        u.h[1] = __builtin_amdgcn_cvt_pkrtz(a[2] * QSC, a[3] * QSC);
        u.h[2] = __builtin_amdgcn_cvt_pkrtz(bb[0] * QSC, bb[1] * QSC);
        u.h[3] = __builtin_amdgcn_cvt_pkrtz(bb[2] * QSC, bb[3] * QSC);
        qf[qg][kk] = u.v;
      }
    }
  }

  f4 o[4][4];
  float l[4];
  #pragma unroll
  for (int qg = 0; qg < 4; ++qg) {
    l[qg] = 0.f;
    #pragma unroll
    for (int oc = 0; oc < 4; ++oc) o[qg][oc] = (f4){0.f, 0.f, 0.f, 0.f};
  }

  int dkt[4], dcc[4];
  #pragma unroll
  for (int qg = 0; qg < 4; ++qg) {
    const int qr = qbase + qg * 16;
    dkt[qg] = qr >> 5; dcc[qg] = (qr >> 4) & 1;
  }
  f4 fdiag;
  #pragma unroll
  for (int r = 0; r < 4; ++r)
    fdiag[r] = (g == (c >> 2) && (c & 3) == r) ? DIAGL : 0.f;

  // --- f16 staging geometry: 16B/thread per tensor ---
  const int krow = tid >> 3, kd8 = (tid & 7) * 8;
  const _Float16* khp = Kh + ((size_t)bh * S + krow) * Dd + kd8;
  const int vd = tid >> 2, vp8 = (tid & 3) * 8;
  const _Float16* vgp = Vg + (((size_t)bh * 64) * Dd + vd) * 32 + vp8;

  h8v krv, vrv;
  auto LOADT = [&](int kt) {
    krv = *(const h8v*)(khp + (size_t)kt * 32 * Dd);
    vrv = *(const h8v*)(vgp + (size_t)kt * Dd * 32);
  };
  auto WRITET = [&](int bf) {
    *(h8v*)&Kf[bf][krow][kd8] = krv;
    *(h8v*)&Vt[bf][vd][vp8] = vrv;
  };

  auto EXPQ = [&](int qg, int kt, f4 s0, f4 s1, h8v& paO) {
    if (kt == dkt[qg]) {
      if (dcc[qg]) s1 += fdiag; else s0 += fdiag;
    }
    float e0 = __builtin_amdgcn_exp2f(s0[0]), e1 = __builtin_amdgcn_exp2f(s0[1]);
    float e2 = __builtin_amdgcn_exp2f(s0[2]), e3 = __builtin_amdgcn_exp2f(s0[3]);
    float e4 = __builtin_amdgcn_exp2f(s1[0]), e5 = __builtin_amdgcn_exp2f(s1[1]);
    float e6 = __builtin_amdgcn_exp2f(s1[2]), e7 = __builtin_amdgcn_exp2f(s1[3]);
    l[qg] += ((e0 + e1) + (e2 + e3)) + ((e4 + e5) + (e6 + e7));
    H8U u;
    u.h[0] = __builtin_amdgcn_cvt_pkrtz(e0, e1);
    u.h[1] = __builtin_amdgcn_cvt_pkrtz(e2, e3);
    u.h[2] = __builtin_amdgcn_cvt_pkrtz(e4, e5);
    u.h[3] = __builtin_amdgcn_cvt_pkrtz(e6, e7);
    paO = u.v;
  };

  h8v paA[4], paB[4], vfA[4], vfB[4];

  auto BODY = [&](int kt, int cur, h8v (&paIn)[4], h8v (&vfIn)[4],
                  h8v (&paOut)[4], h8v (&vfOut)[4]) {
    h8v ka[2][2];
    #pragma unroll
    for (int cc = 0; cc < 2; ++cc)
      #pragma unroll
      for (int kk = 0; kk < 2; ++kk)
        ka[cc][kk] = *(const h8v*)&Kf[cur][cc * 16 + c][g * 16 + kk * 8];
    #pragma unroll
    for (int oc = 0; oc < 4; ++oc) {
      const int fd = ((oc * 16 + c) >> 3) & 3;
      vfOut[oc] = *(const h8v*)&Vt[cur][oc * 16 + c][(g ^ fd) << 3];
    }

    f4 s0[4], s1[4];
    __builtin_amdgcn_s_setprio(1);
    #pragma unroll
    for (int qg = 0; qg < 2; ++qg) {
      s0[qg] = (f4){0.f, 0.f, 0.f, 0.f}; s1[qg] = (f4){0.f, 0.f, 0.f, 0.f};
      s0[qg] = __builtin_amdgcn_mfma_f32_16x16x32_f16(ka[0][0], qf[qg][0], s0[qg], 0, 0, 0);
      s0[qg] = __builtin_amdgcn_mfma_f32_16x16x32_f16(ka[0][1], qf[qg][1], s0[qg], 0, 0, 0);
      s1[qg] = __builtin_amdgcn_mfma_f32_16x16x32_f16(ka[1][0], qf[qg][0], s1[qg], 0, 0, 0);
      s1[qg] = __builtin_amdgcn_mfma_f32_16x16x32_f16(ka[1][1], qf[qg][1], s1[qg], 0, 0, 0);
    }
    #pragma unroll
    for (int qg = 0; qg < 2; ++qg)
      #pragma unroll
      for (int oc = 0; oc < 4; ++oc)
        o[qg][oc] = __builtin_amdgcn_mfma_f32_16x16x32_f16(paIn[qg], vfIn[oc], o[qg][oc], 0, 0, 0);
    EXPQ(0, kt, s0[0], s1[0], paOut[0]);
    EXPQ(1, kt, s0[1], s1[1], paOut[1]);
    #pragma unroll
    for (int qg = 2; qg < 4; ++qg) {
      s0[qg] = (f4){0.f, 0.f, 0.f, 0.f}; s1[qg] = (f4){0.f, 0.f, 0.f, 0.f};
      s0[qg] = __builtin_amdgcn_mfma_f32_16x16x32_f16(ka[0][0], qf[qg][0], s0[qg], 0, 0, 0);
      s0[qg] = __builtin_amdgcn_mfma_f32_16x16x32_f16(ka[0][1], qf[qg][1], s0[qg], 0, 0, 0);
      s1[qg] = __builtin_amdgcn_mfma_f32_16x16x32_f16(ka[1][0], qf[qg][0], s1[qg], 0, 0, 0);
      s1[qg] = __builtin_amdgcn_mfma_f32_16x16x32_f16(ka[1][1], qf[qg][1], s1[qg], 0, 0, 0);
    }
    #pragma unroll
    for (int qg = 2; qg < 4; ++qg)
      #pragma unroll
      for (int oc = 0; oc < 4; ++oc)
        o[qg][oc] = __builtin_amdgcn_mfma_f32_16x16x32_f16(paIn[qg], vfIn[oc], o[qg][oc], 0, 0, 0);
    __builtin_amdgcn_s_setprio(0);
    EXPQ(2, kt, s0[2], s1[2], paOut[2]);
    EXPQ(3, kt, s0[3], s1[3], paOut[3]);

    if (kt < NKT - 1) WRITET(1 - cur);
    if (kt < NKT - 2) LOADT(kt + 2);
    // raw barrier: drain LDS only; global prefetch loads stay in flight.
    asm volatile("s_waitcnt lgkmcnt(0)" ::: "memory");
    __builtin_amdgcn_sched_barrier(0);
    __builtin_amdgcn_s_barrier();
    __builtin_amdgcn_sched_barrier(0);
  };

  // --- prologue ---
  LOADT(0);
  WRITET(0);
  LOADT(1);
  __syncthreads();
  {
    h8v ka[2][2];
    #pragma unroll
    for (int cc = 0; cc < 2; ++cc)
      #pragma unroll
      for (int kk = 0; kk < 2; ++kk)
        ka[cc][kk] = *(const h8v*)&Kf[0][cc * 16 + c][g * 16 + kk * 8];
    #pragma unroll
    for (int oc = 0; oc < 4; ++oc) {
      const int fd = ((oc * 16 + c) >> 3) & 3;
      vfA[oc] = *(const h8v*)&Vt[0][oc * 16 + c][(g ^ fd) << 3];
    }
    #pragma unroll
    for (int qg = 0; qg < 4; ++qg) {
      f4 s0 = (f4){0.f, 0.f, 0.f, 0.f}, s1 = (f4){0.f, 0.f, 0.f, 0.f};
      s0 = __builtin_amdgcn_mfma_f32_16x16x32_f16(ka[0][0], qf[qg][0], s0, 0, 0, 0);
      s0 = __builtin_amdgcn_mfma_f32_16x16x32_f16(ka[0][1], qf[qg][1], s0, 0, 0, 0);
      s1 = __builtin_amdgcn_mfma_f32_16x16x32_f16(ka[1][0], qf[qg][0], s1, 0, 0, 0);
      s1 = __builtin_amdgcn_mfma_f32_16x16x32_f16(ka[1][1], qf[qg][1], s1, 0, 0, 0);
      EXPQ(qg, 0, s0, s1, paA[qg]);
    }
    WRITET(1);
    LOADT(2);
    __syncthreads();
  }

  for (int kt = 1; kt < NKT - 1; kt += 2) {
    BODY(kt,     1, paA, vfA, paB, vfB);
    BODY(kt + 1, 0, paB, vfB, paA, vfA);
  }
  BODY(NKT - 1, 1, paA, vfA, paB, vfB);

  #pragma unroll
  for (int oc = 0; oc < 4; ++oc)
    #pragma unroll
    for (int qg = 0; qg < 4; ++qg)
      o[qg][oc] = __builtin_amdgcn_mfma_f32_16x16x32_f16(paB[qg], vfB[oc], o[qg][oc], 0, 0, 0);

  #pragma unroll
  for (int qg = 0; qg < 4; ++qg) {
    float lv = l[qg];
    lv += __shfl_xor(lv, 16);
    lv += __shfl_xor(lv, 32);
    const float invl = 1.0f / lv;
    #pragma unroll
    for (int r = 0; r < 4; ++r) {
      const float inv = __shfl(invl, g * 4 + r);
      float* op = out + (((size_t)b * S + qbase + qg * 16 + g * 4 + r) * H + h) * Dd + c;
      #pragma unroll
      for (int oc = 0; oc < 4; ++oc)
        op[oc * 16] = o[qg][oc][r] * inv;
    }
  }
}

extern "C" void kernel_launch(void* const* d_in, const int* in_sizes, int n_in,
                              void* d_out, int out_size, void* d_ws, size_t ws_size,
                              hipStream_t stream) {
  const float* q = (const float*)d_in[0];
  const float* k = (const float*)d_in[1];
  const float* v = (const float*)d_in[2];
  float* out = (float*)d_out;
  _Float16* Kh = (_Float16*)d_ws;            // 16 MB
  _Float16* Vg = Kh + KH_ELEMS;              // 16 MB (ws >= 34.6 MB proven in R11)
  prep<<<dim3(512), 256, 0, stream>>>(k, v, Kh, Vg);
  attn_fwd<<<dim3(512), 256, 0, stream>>>(q, Kh, Vg, out);
}